// Round 1
// 4176.136 us; speedup vs baseline: 4.0195x; 4.0195x over previous
//
#include <hip/hip_runtime.h>
#include <hip/hip_bf16.h>

typedef __hip_bfloat16 bf16;
typedef __attribute__((ext_vector_type(8))) short short8;
typedef __attribute__((ext_vector_type(4))) short sv4;
typedef __attribute__((ext_vector_type(4))) float f32x4;
typedef __attribute__((ext_vector_type(4))) unsigned uint4v;

#define NTHR 512
#define OUT_EMB 16777216ul   // T*L*B*IN floats

__device__ __forceinline__ float sgm(float x) { return 1.0f / (1.0f + expf(-x)); }
__device__ __forceinline__ short8 ld8(const bf16* p) {
  return *reinterpret_cast<const short8*>(p);
}

// kb-layout slab (64 rows x 1024 cols): element (row,col) at ((col>>2)*64+row)*4 + (col&3)
// -> each block's 4 owned columns are a contiguous 512B line-exclusive region per slab.
__device__ __forceinline__ short8 ld8kb(const bf16* slab, int row, int col) {
  const sv4* p = reinterpret_cast<const sv4*>(slab) + ((col >> 2) * 64 + row);
  sv4 a = p[0], b = p[64];
  return __builtin_shufflevector(a, b, 0, 1, 2, 3, 4, 5, 6, 7);
}

// ---- plain bf16 wave MMA: D[MT*16,16] += A[MT*16,kk] @ W[16,kk]^T ----
template<int MT>
__device__ __forceinline__ void wave_mma_bf(const bf16* __restrict__ A, int lda,
                                            const bf16* __restrict__ W, int ldw,
                                            int kk, f32x4* acc, int lane) {
  const int m = lane & 15, ko = (lane >> 4) * 8;
  const bf16* ap = A + (size_t)m * lda + ko;
  const bf16* wp = W + (size_t)m * ldw + ko;
#pragma unroll 4
  for (int k = 0; k < kk; k += 32) {
    short8 b = ld8(wp + k);
#pragma unroll
    for (int mt = 0; mt < MT; ++mt) {
      short8 a = ld8(ap + (size_t)mt * 16 * lda + k);
      acc[mt] = __builtin_amdgcn_mfma_f32_16x16x32_bf16(a, b, acc[mt], 0, 0, 0);
    }
  }
}

// ---- f32-A split MMA (prologue wfused only) ----
template<int MT>
__device__ __forceinline__ void wave_mma_f32a(const float* __restrict__ A, int lda,
                                              const bf16* __restrict__ W, int ldw,
                                              int kk, f32x4* acc, int lane) {
  const int m = lane & 15, ko = (lane >> 4) * 8;
  const float* ap = A + (size_t)m * lda + ko;
  const short* wp = reinterpret_cast<const short*>(W) + (size_t)m * ldw + ko;
#pragma unroll 2
  for (int k = 0; k < kk; k += 32) {
    short8 b = *reinterpret_cast<const short8*>(wp + k);
#pragma unroll
    for (int mt = 0; mt < MT; ++mt) {
      const float* s = ap + (size_t)mt * 16 * lda + k;
      float4 x0 = *reinterpret_cast<const float4*>(s);
      float4 x1 = *reinterpret_cast<const float4*>(s + 4);
      float xs[8] = {x0.x, x0.y, x0.z, x0.w, x1.x, x1.y, x1.z, x1.w};
      short8 ahi, alo;
#pragma unroll
      for (int j = 0; j < 8; ++j) {
        unsigned u  = __builtin_bit_cast(unsigned, xs[j]);
        float hf    = __builtin_bit_cast(float, u & 0xFFFF0000u);
        unsigned ul = __builtin_bit_cast(unsigned, xs[j] - hf);
        ahi[j] = (short)(u >> 16);
        alo[j] = (short)(ul >> 16);
      }
      acc[mt] = __builtin_amdgcn_mfma_f32_16x16x32_bf16(ahi, b, acc[mt], 0, 0, 0);
      acc[mt] = __builtin_amdgcn_mfma_f32_16x16x32_bf16(alo, b, acc[mt], 0, 0, 0);
    }
  }
}

// ---------------- prologue kernels ----------------

__global__ void embed_kernel(const int* __restrict__ tgt, const float* __restrict__ table,
                             float* __restrict__ embout, bf16* __restrict__ embbf,
                             unsigned* __restrict__ arrive) {
  const int row = blockIdx.x;                  // t*64+b
  const int tok = tgt[row];
  const float2* src = reinterpret_cast<const float2*>(table + (size_t)tok * 512);
  float2 v = src[threadIdx.x];
  reinterpret_cast<float2*>(embout + (size_t)row * 512)[threadIdx.x] = v;
  ushort2 h;
  h.x = __builtin_bit_cast(unsigned short, __float2bfloat16(v.x));
  h.y = __builtin_bit_cast(unsigned short, __float2bfloat16(v.y));
  reinterpret_cast<ushort2*>(embbf + (size_t)row * 512)[threadIdx.x] = h;
  if (row == 0 && threadIdx.x < 256) arrive[threadIdx.x] = 0;
}

__global__ void cvt_bf16_kernel(const float* __restrict__ src, bf16* __restrict__ dst, int n) {
  const int i = blockIdx.x * blockDim.x + threadIdx.x;
  if (i < n) dst[i] = __float2bfloat16(src[i]);
}

// h0/h1 initial state in kb-layout
__global__ void init_h_kernel(const float* __restrict__ h0in,
                              bf16* __restrict__ h0a, bf16* __restrict__ h1a) {
  const int idx = blockIdx.x * blockDim.x + threadIdx.x;   // 131072
  const int layer = idx >> 16, e = idx & 65535;
  const int b = e >> 10, col = e & 1023;
  bf16 v = __float2bfloat16(h0in[(size_t)layer * 65536 + e]);
  const size_t off = ((size_t)(col >> 2) * 64 + b) * 4 + (col & 3);
  if (layer) h1a[off] = v; else h0a[off] = v;
}

// wp0t_{hi,lo}[k][j] = split(Wp0[j][k])
__global__ void transpose_kernel(const float* __restrict__ Wp0,
                                 bf16* __restrict__ thi, bf16* __restrict__ tlo) {
  const int k = blockIdx.x;
  for (int j = threadIdx.x; j < 512; j += blockDim.x) {
    const float x = Wp0[(size_t)j * 1024 + k];
    const bf16 h = __float2bfloat16(x);
    thi[(size_t)k * 512 + j] = h;
    tlo[(size_t)k * 512 + j] = __float2bfloat16(x - __bfloat162float(h));
  }
}

// wfub[n][k] = bf16( sum_j Wih1[n][j] * Wp0[j][k] )
__global__ void wfused_kernel(const float* __restrict__ Wih1, const bf16* __restrict__ thi,
                              const bf16* __restrict__ tlo, bf16* __restrict__ wfub) {
  const int bx = blockIdx.x & 63, by = blockIdx.x >> 6;
  const int wv = threadIdx.x >> 6, lane = threadIdx.x & 63;
  const f32x4 vz = {0.f, 0.f, 0.f, 0.f};
  f32x4 acc[4] = {vz, vz, vz, vz};
  wave_mma_f32a<4>(Wih1 + (size_t)bx * 64 * 512, 512,
                   thi + (size_t)(by * 64 + wv * 16) * 512, 512, 512, acc, lane);
  wave_mma_f32a<4>(Wih1 + (size_t)bx * 64 * 512, 512,
                   tlo + (size_t)(by * 64 + wv * 16) * 512, 512, 512, acc, lane);
  const int cc = lane & 15, qq = lane >> 4;
#pragma unroll
  for (int mt = 0; mt < 4; ++mt)
#pragma unroll
    for (int rg = 0; rg < 4; ++rg)
      wfub[(size_t)(bx * 64 + mt * 16 + qq * 4 + rg) * 1024 + by * 64 + wv * 16 + cc] =
          __float2bfloat16(acc[mt][rg]);
}

// bfx[n] = bih1[n] + bhh1[n] + sum_j Wih1[n][j]*bp0[j]
__global__ void bfx_kernel(const float* __restrict__ Wih1, const float* __restrict__ bp0,
                           const float* __restrict__ bih1, const float* __restrict__ bhh1,
                           float* __restrict__ bfx) {
  const int n = blockIdx.x * blockDim.x + threadIdx.x;
  float s = bih1[n] + bhh1[n];
  for (int j = 0; j < 512; ++j)
    s += Wih1[(size_t)n * 512 + j] * bp0[j];
  bfx[n] = s;
}

// pre0 in block-exclusive layout: pre0[(((t*256+bid)*64+row)*4 + j2)*4 + gi]
__global__ void pre0_gemm_kernel(const bf16* __restrict__ embbf, const bf16* __restrict__ wih0b,
                                 const float* __restrict__ bih0, const float* __restrict__ bhh0,
                                 bf16* __restrict__ pre0) {
  const int ct = blockIdx.x & 63, rt = blockIdx.x >> 6;   // 64 col-tiles fastest
  const int wv = threadIdx.x >> 6, lane = threadIdx.x & 63;
  const f32x4 vz = {0.f, 0.f, 0.f, 0.f};
  f32x4 acc[4] = {vz, vz, vz, vz};
  wave_mma_bf<4>(embbf + (size_t)rt * 64 * 512, 512,
                 wih0b + (size_t)(ct * 64 + wv * 16) * 512, 512, 512, acc, lane);
  const int cc = lane & 15, qq = lane >> 4;
#pragma unroll
  for (int mt = 0; mt < 4; ++mt)
#pragma unroll
    for (int rg = 0; rg < 4; ++rg) {
      const int n = ct * 64 + wv * 16 + cc;
      const size_t R = (size_t)rt * 64 + mt * 16 + qq * 4 + rg;
      const int t = (int)(R >> 6), brow = (int)(R & 63);
      const int gi = n >> 10, c10 = n & 1023;
      pre0[((((size_t)t * 256 + (c10 >> 2)) * 64 + brow) * 4 + (c10 & 3)) * 4 + gi] =
          __float2bfloat16(acc[mt][rg] + bih0[n] + bhh0[n]);
    }
}

// out[t][l][brow][col] = h_l(t+1)[brow] @ Wp_l[col]^T + bp_l[col]   (h in kb-layout)
__global__ void proj_kernel(const bf16* __restrict__ h0a, const bf16* __restrict__ h1a,
                            const bf16* __restrict__ wp0b, const bf16* __restrict__ wp1b,
                            const float* __restrict__ bp0, const float* __restrict__ bp1,
                            float* __restrict__ out) {
  const int l = blockIdx.y;
  const bf16* hbase = (l ? h1a : h0a) + 65536;       // slab 1 onward
  const bf16* wp = l ? wp1b : wp0b;
  const float* bp = l ? bp1 : bp0;
  const int ct = blockIdx.x & 7, rt = blockIdx.x >> 3;
  const int wv = threadIdx.x >> 6, lane = threadIdx.x & 63;
  const f32x4 vz = {0.f, 0.f, 0.f, 0.f};
  f32x4 acc[4] = {vz, vz, vz, vz};
  const int m = lane & 15, ko = (lane >> 4) * 8;
  const bf16* wpp = wp + (size_t)(ct * 64 + wv * 16 + m) * 1024 + ko;
#pragma unroll 4
  for (int k = 0; k < 1024; k += 32) {
    short8 b = ld8(wpp + k);
#pragma unroll
    for (int mt = 0; mt < 4; ++mt) {
      const int R = rt * 64 + mt * 16 + m;
      const bf16* slab = hbase + (size_t)(R >> 6) * 65536;
      short8 a = ld8kb(slab, R & 63, ko + k);
      acc[mt] = __builtin_amdgcn_mfma_f32_16x16x32_bf16(a, b, acc[mt], 0, 0, 0);
    }
  }
  const int cc = lane & 15, qq = lane >> 4;
#pragma unroll
  for (int mt = 0; mt < 4; ++mt)
#pragma unroll
    for (int rg = 0; rg < 4; ++rg) {
      const int R = rt * 64 + mt * 16 + qq * 4 + rg;
      const int t = R >> 6, brow = R & 63;
      const int col = ct * 64 + wv * 16 + cc;
      out[((size_t)t * 2 + l) * 32768 + (size_t)brow * 512 + col] = acc[mt][rg] + bp[col];
    }
}

// ---------------- persistent recurrent kernel (fused layer pipeline) ----------------
// 256 blocks x 512 thr; block bid owns h-cols [bid*4, bid*4+4) of both layers.
// Superstep s: layer0 step s (reads h0a[s]) AND layer1 step s-1 (reads h0a[s], h1a[s-1]).
// One global barrier per superstep (256 total, was 512).
// h slabs + pre0 are in block-line-exclusive layouts => no stale L2/L1 copies can exist
// => per-superstep acquire fence (buffer_inv) is dropped; release (wbl2) kept.
__global__ void __launch_bounds__(NTHR, 2)
lstm_kernel(const float* __restrict__ c0in,
            const bf16* __restrict__ whh0b, const bf16* __restrict__ wfub,
            const bf16* __restrict__ whh1b, const float* __restrict__ bfx,
            const bf16* __restrict__ pre0,  // block-exclusive layout
            bf16* __restrict__ h0a,         // [257] slabs, kb-layout
            bf16* __restrict__ h1a,         // [257] slabs, kb-layout
            unsigned* __restrict__ arrive)
{
  __shared__ float red[2][4][16][17];
  __shared__ short wl[16384];                // Whh1 slice [32ks][16col][32e] = 32 KB
  const int bid = blockIdx.x, tid = threadIdx.x;
  const int wv = tid >> 6, lane = tid & 63;
  const int rg = wv & 3, kh = wv >> 2;       // row-group, K-half
  const int cc = lane & 15, q = lane >> 4;
  const int nrow = (cc >> 2) * 1024 + bid * 4 + (cc & 3);  // gate-col index
  const f32x4 vz = {0.f, 0.f, 0.f, 0.f};
  unsigned target = 0;

  // --- preload weights ---
  short8 wfA[16], wfB[16];
#pragma unroll
  for (int ks = 0; ks < 16; ++ks) {
    wfA[ks] = ld8(whh0b + (size_t)nrow * 1024 + kh * 512 + ks * 32 + q * 8);
    wfB[ks] = ld8(wfub  + (size_t)nrow * 1024 + kh * 512 + ks * 32 + q * 8);
  }
  for (int e8 = tid * 8; e8 < 16384; e8 += NTHR * 8) {
    const int ks = e8 >> 9, col = (e8 >> 5) & 15, ko = e8 & 31;
    const int nr = (col >> 2) * 1024 + bid * 4 + (col & 3);
    *reinterpret_cast<short8*>(wl + e8) = ld8(whh1b + (size_t)nr * 1024 + ks * 32 + ko);
  }

  // --- per-thread elementwise state: low waves (tid<256) own layer0, high own layer1 ---
  const bool lowT = tid < 256;
  const int et = tid & 255, row = et >> 2, j2 = et & 3;
  float cS, bfxr[4];
  if (lowT) {
    cS = c0in[(size_t)row * 1024 + bid * 4 + j2];
  } else {
    cS = c0in[65536 + (size_t)row * 1024 + bid * 4 + j2];
#pragma unroll
    for (int gi = 0; gi < 4; ++gi) bfxr[gi] = bfx[gi * 1024 + bid * 4 + j2];
  }

  __syncthreads();   // wl (LDS) ready; no initial global barrier needed

  auto barrier = [&]() {
    ++target;
    __syncthreads();   // compiler drains vmcnt before s_barrier -> all h stores in L2
    if (tid == 0)      // release: wbl2 (few dirty lines) + store flag to IF
      __hip_atomic_store(&arrive[bid], target, __ATOMIC_RELEASE, __HIP_MEMORY_SCOPE_AGENT);
    if (tid < 64) {
      const unsigned* ap = arrive + tid * 4;
      for (;;) {
        uint4v v;
        asm volatile("global_load_dwordx4 %0, %1, off sc1\n\ts_waitcnt vmcnt(0)"
                     : "=&v"(v) : "v"(ap) : "memory");
        if (v[0] >= target && v[1] >= target && v[2] >= target && v[3] >= target) break;
        __builtin_amdgcn_s_sleep(1);
      }
    }
    __syncthreads();
    // NOTE: no acquire fence: every h/pre0 line is single-writer and write-once,
    // first-touched by readers only after the global barrier => no stale copies.
  };

  const int arow = rg * 16 + cc, kbase = kh * 512 + q * 8;
  const short* wlw = wl + (kh * 16) * 512 + cc * 32 + q * 8;

  for (int s = 0; s <= 256; ++s) {
    // prefetch this superstep's layer-0 pre-activations (no cross-step dependency,
    // issued before the MFMA block so latency hides under compute)
    float pg[4];
    if (lowT && s < 256) {
      const bf16* pp = pre0 + ((((size_t)s * 256 + bid) * 64 + row) * 4 + j2) * 4;
#pragma unroll
      for (int gi = 0; gi < 4; ++gi) pg[gi] = __bfloat162float(pp[gi]);
    }

    f32x4 accA = vz, accB = vz;
    const bf16* s0 = h0a + (size_t)s * 65536;
    if (s < 256) {
#pragma unroll
      for (int ks = 0; ks < 16; ++ks) {
        short8 a = ld8kb(s0, arow, kbase + ks * 32);   // one h0 load feeds both layers
        accA = __builtin_amdgcn_mfma_f32_16x16x32_bf16(a, wfA[ks], accA, 0, 0, 0);
        accB = __builtin_amdgcn_mfma_f32_16x16x32_bf16(a, wfB[ks], accB, 0, 0, 0);
      }
    } else {
#pragma unroll
      for (int ks = 0; ks < 16; ++ks) {
        short8 a = ld8kb(s0, arow, kbase + ks * 32);
        accB = __builtin_amdgcn_mfma_f32_16x16x32_bf16(a, wfB[ks], accB, 0, 0, 0);
      }
    }
    if (s > 0) {
      const bf16* s1 = h1a + (size_t)(s - 1) * 65536;
#pragma unroll
      for (int ks = 0; ks < 16; ++ks)
        accB = __builtin_amdgcn_mfma_f32_16x16x32_bf16(
            ld8kb(s1, arow, kbase + ks * 32),
            *reinterpret_cast<const short8*>(wlw + ks * 512), accB, 0, 0, 0);
    }

    // fused dual reduction over K-halves
    if (kh == 1) {
#pragma unroll
      for (int r = 0; r < 4; ++r) {
        red[0][rg][q * 4 + r][cc] = accA[r];
        red[1][rg][q * 4 + r][cc] = accB[r];
      }
    }
    __syncthreads();
    if (kh == 0) {
#pragma unroll
      for (int r = 0; r < 4; ++r) {
        red[0][rg][q * 4 + r][cc] += accA[r];
        red[1][rg][q * 4 + r][cc] += accB[r];
      }
    }
    __syncthreads();

    // elementwise split: waves 0-3 layer0, waves 4-7 layer1
    const int rgE = row >> 4, r2 = row & 15;
    if (lowT) {
      if (s < 256) {
        float g[4];
#pragma unroll
        for (int gi = 0; gi < 4; ++gi) g[gi] = red[0][rgE][r2][gi * 4 + j2] + pg[gi];
        const float ii = sgm(g[0]), ff = sgm(g[1]), gg = tanhf(g[2]), oo = sgm(g[3]);
        cS = ff * cS + ii * gg;
        h0a[(size_t)(s + 1) * 65536 + ((size_t)bid * 64 + row) * 4 + j2] =
            __float2bfloat16(oo * tanhf(cS));
      }
    } else {
      if (s > 0) {
        float g[4];
#pragma unroll
        for (int gi = 0; gi < 4; ++gi) g[gi] = red[1][rgE][r2][gi * 4 + j2] + bfxr[gi];
        const float ii = sgm(g[0]), ff = sgm(g[1]), gg = tanhf(g[2]), oo = sgm(g[3]);
        cS = ff * cS + ii * gg;
        h1a[(size_t)s * 65536 + ((size_t)bid * 64 + row) * 4 + j2] =
            __float2bfloat16(oo * tanhf(cS));
      }
    }
    if (s < 256) barrier();
  }
}

extern "C" void kernel_launch(void* const* d_in, const int* in_sizes, int n_in,
                              void* d_out, int out_size, void* d_ws, size_t ws_size,
                              hipStream_t stream) {
  (void)in_sizes; (void)n_in; (void)out_size; (void)ws_size;
  const int*   tgt  = (const int*)d_in[0];
  const float* h0in = (const float*)d_in[1];
  const float* c0in = (const float*)d_in[2];
  const float* table= (const float*)d_in[3];
  const float* Wih0 = (const float*)d_in[4];
  const float* Whh0 = (const float*)d_in[5];
  const float* bih0 = (const float*)d_in[6];
  const float* bhh0 = (const float*)d_in[7];
  const float* Wp0  = (const float*)d_in[8];
  const float* bp0  = (const float*)d_in[9];
  const float* Wih1 = (const float*)d_in[10];
  const float* Whh1 = (const float*)d_in[11];
  const float* bih1 = (const float*)d_in[12];
  const float* bhh1 = (const float*)d_in[13];
  const float* Wp1  = (const float*)d_in[14];
  const float* bp1  = (const float*)d_in[15];
  float* out = (float*)d_out;

  char* w = (char*)d_ws;
  size_t off = 0;
  auto alloc = [&](size_t bytes) { char* p = w + off; off += (bytes + 255) & ~255ul; return p; };
  unsigned* arrive = (unsigned*)alloc(1024);
  float* bfx    = (float*)alloc(4096 * 4);
  bf16* embbf   = (bf16*)alloc(16384ul * 512 * 2);
  bf16* h0a     = (bf16*)alloc(257ul * 65536 * 2);
  bf16* h1a     = (bf16*)alloc(257ul * 65536 * 2);
  bf16* pre0    = (bf16*)alloc(16384ul * 4096 * 2);
  bf16* whh0b   = (bf16*)alloc(4096ul * 1024 * 2);
  bf16* whh1b   = (bf16*)alloc(4096ul * 1024 * 2);
  bf16* wih0b   = (bf16*)alloc(4096ul * 512 * 2);
  bf16* wp0b    = (bf16*)alloc(512ul * 1024 * 2);
  bf16* wp1b    = (bf16*)alloc(512ul * 1024 * 2);
  bf16* wfub    = (bf16*)alloc(4096ul * 1024 * 2);
  bf16* wp0thi  = (bf16*)alloc(1024ul * 512 * 2);
  bf16* wp0tlo  = (bf16*)alloc(1024ul * 512 * 2);

  embed_kernel<<<16384, 256, 0, stream>>>(tgt, table, out + OUT_EMB, embbf, arrive);
  cvt_bf16_kernel<<<16384, 256, 0, stream>>>(Whh0, whh0b, 4096 * 1024);
  cvt_bf16_kernel<<<16384, 256, 0, stream>>>(Whh1, whh1b, 4096 * 1024);
  cvt_bf16_kernel<<<8192, 256, 0, stream>>>(Wih0, wih0b, 4096 * 512);
  cvt_bf16_kernel<<<2048, 256, 0, stream>>>(Wp0, wp0b, 512 * 1024);
  cvt_bf16_kernel<<<2048, 256, 0, stream>>>(Wp1, wp1b, 512 * 1024);
  init_h_kernel<<<512, 256, 0, stream>>>(h0in, h0a, h1a);
  transpose_kernel<<<1024, 256, 0, stream>>>(Wp0, wp0thi, wp0tlo);
  wfused_kernel<<<1024, 256, 0, stream>>>(Wih1, wp0thi, wp0tlo, wfub);
  bfx_kernel<<<16, 256, 0, stream>>>(Wih1, bp0, bih1, bhh1, bfx);
  pre0_gemm_kernel<<<16384, 256, 0, stream>>>(embbf, wih0b, bih0, bhh0, pre0);
  lstm_kernel<<<256, NTHR, 0, stream>>>(c0in, whh0b, wfub, whh1b, bfx, pre0,
                                        h0a, h1a, arrive);
  dim3 pg(2048, 2);
  proj_kernel<<<pg, 256, 0, stream>>>(h0a, h1a, wp0b, wp1b, bp0, bp1, out);
}

// Round 2
// 3587.670 us; speedup vs baseline: 4.6788x; 1.1640x over previous
//
#include <hip/hip_runtime.h>
#include <hip/hip_bf16.h>

typedef __hip_bfloat16 bf16;
typedef __attribute__((ext_vector_type(8))) short short8;
typedef __attribute__((ext_vector_type(4))) short sv4;
typedef __attribute__((ext_vector_type(4))) float f32x4;
typedef __attribute__((ext_vector_type(4))) unsigned uint4v;

#define NTHR 512
#define OUT_EMB 16777216ul   // T*L*B*IN floats

__device__ __forceinline__ float sgm(float x) { return 1.0f / (1.0f + expf(-x)); }
__device__ __forceinline__ short8 ld8(const bf16* p) {
  return *reinterpret_cast<const short8*>(p);
}

// device-coherent write-through store (no dirty L2 line -> no wbl2 needed at release)
__device__ __forceinline__ void st_wt16(bf16* p, float x) {
  unsigned v = (unsigned)__builtin_bit_cast(unsigned short, __float2bfloat16(x));
  asm volatile("global_store_short %0, %1, off sc0 sc1" :: "v"(p), "v"(v) : "memory");
}

// kb-layout slab (64 rows x 1024 cols): element (row,col) at ((col>>2)*64+row)*4 + (col&3)
// -> each block's 4 owned columns are a contiguous 512B line-exclusive region per slab.
__device__ __forceinline__ short8 ld8kb(const bf16* slab, int row, int col) {
  const sv4* p = reinterpret_cast<const sv4*>(slab) + ((col >> 2) * 64 + row);
  sv4 a = p[0], b = p[64];
  return __builtin_shufflevector(a, b, 0, 1, 2, 3, 4, 5, 6, 7);
}

// ---- plain bf16 wave MMA: D[MT*16,16] += A[MT*16,kk] @ W[16,kk]^T ----
template<int MT>
__device__ __forceinline__ void wave_mma_bf(const bf16* __restrict__ A, int lda,
                                            const bf16* __restrict__ W, int ldw,
                                            int kk, f32x4* acc, int lane) {
  const int m = lane & 15, ko = (lane >> 4) * 8;
  const bf16* ap = A + (size_t)m * lda + ko;
  const bf16* wp = W + (size_t)m * ldw + ko;
#pragma unroll 4
  for (int k = 0; k < kk; k += 32) {
    short8 b = ld8(wp + k);
#pragma unroll
    for (int mt = 0; mt < MT; ++mt) {
      short8 a = ld8(ap + (size_t)mt * 16 * lda + k);
      acc[mt] = __builtin_amdgcn_mfma_f32_16x16x32_bf16(a, b, acc[mt], 0, 0, 0);
    }
  }
}

// ---- f32-A split MMA (prologue wfused only) ----
template<int MT>
__device__ __forceinline__ void wave_mma_f32a(const float* __restrict__ A, int lda,
                                              const bf16* __restrict__ W, int ldw,
                                              int kk, f32x4* acc, int lane) {
  const int m = lane & 15, ko = (lane >> 4) * 8;
  const float* ap = A + (size_t)m * lda + ko;
  const short* wp = reinterpret_cast<const short*>(W) + (size_t)m * ldw + ko;
#pragma unroll 2
  for (int k = 0; k < kk; k += 32) {
    short8 b = *reinterpret_cast<const short8*>(wp + k);
#pragma unroll
    for (int mt = 0; mt < MT; ++mt) {
      const float* s = ap + (size_t)mt * 16 * lda + k;
      float4 x0 = *reinterpret_cast<const float4*>(s);
      float4 x1 = *reinterpret_cast<const float4*>(s + 4);
      float xs[8] = {x0.x, x0.y, x0.z, x0.w, x1.x, x1.y, x1.z, x1.w};
      short8 ahi, alo;
#pragma unroll
      for (int j = 0; j < 8; ++j) {
        unsigned u  = __builtin_bit_cast(unsigned, xs[j]);
        float hf    = __builtin_bit_cast(float, u & 0xFFFF0000u);
        unsigned ul = __builtin_bit_cast(unsigned, xs[j] - hf);
        ahi[j] = (short)(u >> 16);
        alo[j] = (short)(ul >> 16);
      }
      acc[mt] = __builtin_amdgcn_mfma_f32_16x16x32_bf16(ahi, b, acc[mt], 0, 0, 0);
      acc[mt] = __builtin_amdgcn_mfma_f32_16x16x32_bf16(alo, b, acc[mt], 0, 0, 0);
    }
  }
}

// ---------------- prologue kernels ----------------

__global__ void embed_kernel(const int* __restrict__ tgt, const float* __restrict__ table,
                             float* __restrict__ embout, bf16* __restrict__ embbf,
                             unsigned* __restrict__ arrive) {
  const int row = blockIdx.x;                  // t*64+b
  const int tok = tgt[row];
  const float2* src = reinterpret_cast<const float2*>(table + (size_t)tok * 512);
  float2 v = src[threadIdx.x];
  reinterpret_cast<float2*>(embout + (size_t)row * 512)[threadIdx.x] = v;
  ushort2 h;
  h.x = __builtin_bit_cast(unsigned short, __float2bfloat16(v.x));
  h.y = __builtin_bit_cast(unsigned short, __float2bfloat16(v.y));
  reinterpret_cast<ushort2*>(embbf + (size_t)row * 512)[threadIdx.x] = h;
  if (row == 0 && threadIdx.x < 256) arrive[threadIdx.x] = 0;
}

__device__ __forceinline__ void cvt4(const float* __restrict__ src, bf16* __restrict__ dst,
                                     int i) {
  float4 v = *reinterpret_cast<const float4*>(src + i);
  sv4 o;
  o[0] = (short)__builtin_bit_cast(unsigned short, __float2bfloat16(v.x));
  o[1] = (short)__builtin_bit_cast(unsigned short, __float2bfloat16(v.y));
  o[2] = (short)__builtin_bit_cast(unsigned short, __float2bfloat16(v.z));
  o[3] = (short)__builtin_bit_cast(unsigned short, __float2bfloat16(v.w));
  *reinterpret_cast<sv4*>(dst + i) = o;
}

// fused weight-conversion + h-init + Wp0-transpose prologue (one launch)
// block ranges: [0,4096) Whh0 | [4096,8192) Whh1 | [8192,10240) Wih0
//               [10240,10752) Wp0 | [10752,11264) Wp1 | [11264,11776) init_h
//               [11776,12800) transpose
__global__ void prep_kernel(const float* __restrict__ Whh0, bf16* __restrict__ whh0b,
                            const float* __restrict__ Whh1, bf16* __restrict__ whh1b,
                            const float* __restrict__ Wih0, bf16* __restrict__ wih0b,
                            const float* __restrict__ Wp0,  bf16* __restrict__ wp0b,
                            const float* __restrict__ Wp1,  bf16* __restrict__ wp1b,
                            const float* __restrict__ h0in, bf16* __restrict__ h0a,
                            bf16* __restrict__ h1a,
                            bf16* __restrict__ wp0thi, bf16* __restrict__ wp0tlo) {
  const int b = blockIdx.x, tid = threadIdx.x;
  if (b < 4096) {
    cvt4(Whh0, whh0b, b * 1024 + tid * 4);
  } else if (b < 8192) {
    cvt4(Whh1, whh1b, (b - 4096) * 1024 + tid * 4);
  } else if (b < 10240) {
    cvt4(Wih0, wih0b, (b - 8192) * 1024 + tid * 4);
  } else if (b < 10752) {
    cvt4(Wp0, wp0b, (b - 10240) * 1024 + tid * 4);
  } else if (b < 11264) {
    cvt4(Wp1, wp1b, (b - 10752) * 1024 + tid * 4);
  } else if (b < 11776) {
    const int idx = (b - 11264) * 256 + tid;          // 131072
    const int layer = idx >> 16, e = idx & 65535;
    const int row = e >> 10, col = e & 1023;
    bf16 v = __float2bfloat16(h0in[(size_t)layer * 65536 + e]);
    const size_t off = ((size_t)(col >> 2) * 64 + row) * 4 + (col & 3);
    if (layer) h1a[off] = v; else h0a[off] = v;
  } else {
    const int k = b - 11776;
    for (int j = tid; j < 512; j += blockDim.x) {
      const float x = Wp0[(size_t)j * 1024 + k];
      const bf16 h = __float2bfloat16(x);
      wp0thi[(size_t)k * 512 + j] = h;
      wp0tlo[(size_t)k * 512 + j] = __float2bfloat16(x - __bfloat162float(h));
    }
  }
}

// wfub[n][k] = bf16( sum_j Wih1[n][j] * Wp0[j][k] )
__global__ void wfused_kernel(const float* __restrict__ Wih1, const bf16* __restrict__ thi,
                              const bf16* __restrict__ tlo, bf16* __restrict__ wfub) {
  const int bx = blockIdx.x & 63, by = blockIdx.x >> 6;
  const int wv = threadIdx.x >> 6, lane = threadIdx.x & 63;
  const f32x4 vz = {0.f, 0.f, 0.f, 0.f};
  f32x4 acc[4] = {vz, vz, vz, vz};
  wave_mma_f32a<4>(Wih1 + (size_t)bx * 64 * 512, 512,
                   thi + (size_t)(by * 64 + wv * 16) * 512, 512, 512, acc, lane);
  wave_mma_f32a<4>(Wih1 + (size_t)bx * 64 * 512, 512,
                   tlo + (size_t)(by * 64 + wv * 16) * 512, 512, 512, acc, lane);
  const int cc = lane & 15, qq = lane >> 4;
#pragma unroll
  for (int mt = 0; mt < 4; ++mt)
#pragma unroll
    for (int rg = 0; rg < 4; ++rg)
      wfub[(size_t)(bx * 64 + mt * 16 + qq * 4 + rg) * 1024 + by * 64 + wv * 16 + cc] =
          __float2bfloat16(acc[mt][rg]);
}

// bfx[n] = bih1[n] + bhh1[n] + sum_j Wih1[n][j]*bp0[j]
__global__ void bfx_kernel(const float* __restrict__ Wih1, const float* __restrict__ bp0,
                           const float* __restrict__ bih1, const float* __restrict__ bhh1,
                           float* __restrict__ bfx) {
  const int n = blockIdx.x * blockDim.x + threadIdx.x;
  float s = bih1[n] + bhh1[n];
  for (int j = 0; j < 512; ++j)
    s += Wih1[(size_t)n * 512 + j] * bp0[j];
  bfx[n] = s;
}

// pre0 in block-exclusive layout: pre0[(((t*256+bid)*64+row)*4 + j2)*4 + gi]
__global__ void pre0_gemm_kernel(const bf16* __restrict__ embbf, const bf16* __restrict__ wih0b,
                                 const float* __restrict__ bih0, const float* __restrict__ bhh0,
                                 bf16* __restrict__ pre0) {
  const int ct = blockIdx.x & 63, rt = blockIdx.x >> 6;   // 64 col-tiles fastest
  const int wv = threadIdx.x >> 6, lane = threadIdx.x & 63;
  const f32x4 vz = {0.f, 0.f, 0.f, 0.f};
  f32x4 acc[4] = {vz, vz, vz, vz};
  wave_mma_bf<4>(embbf + (size_t)rt * 64 * 512, 512,
                 wih0b + (size_t)(ct * 64 + wv * 16) * 512, 512, 512, acc, lane);
  const int cc = lane & 15, qq = lane >> 4;
#pragma unroll
  for (int mt = 0; mt < 4; ++mt)
#pragma unroll
    for (int rg = 0; rg < 4; ++rg) {
      const int n = ct * 64 + wv * 16 + cc;
      const size_t R = (size_t)rt * 64 + mt * 16 + qq * 4 + rg;
      const int t = (int)(R >> 6), brow = (int)(R & 63);
      const int gi = n >> 10, c10 = n & 1023;
      pre0[((((size_t)t * 256 + (c10 >> 2)) * 64 + brow) * 4 + (c10 & 3)) * 4 + gi] =
          __float2bfloat16(acc[mt][rg] + bih0[n] + bhh0[n]);
    }
}

// out[t][l][brow][col] = h_l(t+1)[brow] @ Wp_l[col]^T + bp_l[col]   (h in kb-layout)
__global__ void proj_kernel(const bf16* __restrict__ h0a, const bf16* __restrict__ h1a,
                            const bf16* __restrict__ wp0b, const bf16* __restrict__ wp1b,
                            const float* __restrict__ bp0, const float* __restrict__ bp1,
                            float* __restrict__ out) {
  const int l = blockIdx.y;
  const bf16* hbase = (l ? h1a : h0a) + 65536;       // slab 1 onward
  const bf16* wp = l ? wp1b : wp0b;
  const float* bp = l ? bp1 : bp0;
  const int ct = blockIdx.x & 7, rt = blockIdx.x >> 3;
  const int wv = threadIdx.x >> 6, lane = threadIdx.x & 63;
  const f32x4 vz = {0.f, 0.f, 0.f, 0.f};
  f32x4 acc[4] = {vz, vz, vz, vz};
  const int m = lane & 15, ko = (lane >> 4) * 8;
  const bf16* wpp = wp + (size_t)(ct * 64 + wv * 16 + m) * 1024 + ko;
#pragma unroll 4
  for (int k = 0; k < 1024; k += 32) {
    short8 b = ld8(wpp + k);
#pragma unroll
    for (int mt = 0; mt < 4; ++mt) {
      const int R = rt * 64 + mt * 16 + m;
      const bf16* slab = hbase + (size_t)(R >> 6) * 65536;
      short8 a = ld8kb(slab, R & 63, ko + k);
      acc[mt] = __builtin_amdgcn_mfma_f32_16x16x32_bf16(a, b, acc[mt], 0, 0, 0);
    }
  }
  const int cc = lane & 15, qq = lane >> 4;
#pragma unroll
  for (int mt = 0; mt < 4; ++mt)
#pragma unroll
    for (int rg = 0; rg < 4; ++rg) {
      const int R = rt * 64 + mt * 16 + qq * 4 + rg;
      const int t = R >> 6, brow = R & 63;
      const int col = ct * 64 + wv * 16 + cc;
      out[((size_t)t * 2 + l) * 32768 + (size_t)brow * 512 + col] = acc[mt][rg] + bp[col];
    }
}

// ---------------- persistent recurrent kernel (fused layer pipeline) ----------------
// 256 blocks x 512 thr; block bid owns h-cols [bid*4, bid*4+4) of both layers.
// Superstep s: layer0 step s AND layer1 step s-1; one global barrier per superstep.
// h stores are sc1 write-through (device-coherent at vmcnt-ack) => release needs NO
// buffer_wbl2 L2 walk: per-wave s_waitcnt vmcnt(0) + s_barrier, then tid0 stores the
// flag sc1. Reads stay fence-free (block-line-exclusive write-once layouts).
__global__ void __launch_bounds__(NTHR, 2)
lstm_kernel(const float* __restrict__ c0in,
            const bf16* __restrict__ whh0b, const bf16* __restrict__ wfub,
            const bf16* __restrict__ whh1b, const float* __restrict__ bfx,
            const bf16* __restrict__ pre0,  // block-exclusive layout
            bf16* __restrict__ h0a,         // [257] slabs, kb-layout
            bf16* __restrict__ h1a,         // [257] slabs, kb-layout
            unsigned* __restrict__ arrive)
{
  __shared__ float red[2][4][16][20];        // pad 20: 2-way max on write/read
  __shared__ short wl[16384];                // Whh1 slice [32ks][4q][16cc][8e] = 32 KB
  const int bid = blockIdx.x, tid = threadIdx.x;
  const int wv = tid >> 6, lane = tid & 63;
  const int rg = wv & 3, kh = wv >> 2;       // row-group, K-half
  const int cc = lane & 15, q = lane >> 4;
  const int nrow = (cc >> 2) * 1024 + bid * 4 + (cc & 3);  // gate-col index
  const f32x4 vz = {0.f, 0.f, 0.f, 0.f};
  unsigned target = 0;

  // --- preload weights ---
  short8 wfA[16], wfB[16];
#pragma unroll
  for (int ks = 0; ks < 16; ++ks) {
    wfA[ks] = ld8(whh0b + (size_t)nrow * 1024 + kh * 512 + ks * 32 + q * 8);
    wfB[ks] = ld8(wfub  + (size_t)nrow * 1024 + kh * 512 + ks * 32 + q * 8);
  }
  // wl layout [ks][q][cc][8e]: quarter-wave ds_read_b128 spreads 2-way only
  for (int e8 = tid * 8; e8 < 16384; e8 += NTHR * 8) {
    const int ks = e8 >> 9, rem = e8 & 511;
    const int qq = rem >> 7, col = (rem >> 3) & 15;
    const int nr = (col >> 2) * 1024 + bid * 4 + (col & 3);
    *reinterpret_cast<short8*>(wl + e8) = ld8(whh1b + (size_t)nr * 1024 + ks * 32 + qq * 8);
  }

  // --- per-thread elementwise state: low waves (tid<256) own layer0, high own layer1 ---
  const bool lowT = tid < 256;
  const int et = tid & 255, row = et >> 2, j2 = et & 3;
  float cS, bfxr[4];
  if (lowT) {
    cS = c0in[(size_t)row * 1024 + bid * 4 + j2];
  } else {
    cS = c0in[65536 + (size_t)row * 1024 + bid * 4 + j2];
#pragma unroll
    for (int gi = 0; gi < 4; ++gi) bfxr[gi] = bfx[gi * 1024 + bid * 4 + j2];
  }

  __syncthreads();   // wl (LDS) ready

  auto barrier = [&]() {
    ++target;
    // each wave drains its own sc1 write-through stores (inline-asm stores are NOT
    // tracked by the compiler's waitcnt model, so this is mandatory)
    asm volatile("s_waitcnt vmcnt(0)" ::: "memory");
    __syncthreads();
    if (tid == 0)      // release: data already at coherent point; flag sc1, no wbl2
      asm volatile("global_store_dword %0, %1, off sc0 sc1"
                   :: "v"(arrive + bid), "v"(target) : "memory");
    if (tid < 64) {
      const unsigned* ap = arrive + tid * 4;
      for (;;) {
        uint4v v;
        asm volatile("global_load_dwordx4 %0, %1, off sc1\n\ts_waitcnt vmcnt(0)"
                     : "=&v"(v) : "v"(ap) : "memory");
        if (v[0] >= target && v[1] >= target && v[2] >= target && v[3] >= target) break;
        __builtin_amdgcn_s_sleep(1);
      }
    }
    __syncthreads();
  };

  const int arow = rg * 16 + cc, kbase = kh * 512 + q * 8;
  const short* wlw = wl + (kh * 16) * 512 + q * 128 + cc * 8;

  for (int s = 0; s <= 256; ++s) {
    // prefetch this superstep's layer-0 pre-activations (one 8B load; latency hides
    // under the MFMA block's h loads)
    sv4 pgv;
    if (lowT && s < 256)
      pgv = *reinterpret_cast<const sv4*>(
          pre0 + ((((size_t)s * 256 + bid) * 64 + row) * 4 + j2) * 4);

    f32x4 accA = vz, accB = vz;
    const bf16* s0 = h0a + (size_t)s * 65536;
    if (s < 256) {
#pragma unroll
      for (int ks = 0; ks < 16; ++ks) {
        short8 a = ld8kb(s0, arow, kbase + ks * 32);   // one h0 load feeds both layers
        accA = __builtin_amdgcn_mfma_f32_16x16x32_bf16(a, wfA[ks], accA, 0, 0, 0);
        accB = __builtin_amdgcn_mfma_f32_16x16x32_bf16(a, wfB[ks], accB, 0, 0, 0);
      }
    } else {
#pragma unroll
      for (int ks = 0; ks < 16; ++ks) {
        short8 a = ld8kb(s0, arow, kbase + ks * 32);
        accB = __builtin_amdgcn_mfma_f32_16x16x32_bf16(a, wfB[ks], accB, 0, 0, 0);
      }
    }
    if (s > 0) {
      const bf16* s1 = h1a + (size_t)(s - 1) * 65536;
#pragma unroll
      for (int ks = 0; ks < 16; ++ks)
        accB = __builtin_amdgcn_mfma_f32_16x16x32_bf16(
            ld8kb(s1, arow, kbase + ks * 32),
            *reinterpret_cast<const short8*>(wlw + ks * 512), accB, 0, 0, 0);
    }

    // fused dual reduction over K-halves
    if (kh == 1) {
#pragma unroll
      for (int r = 0; r < 4; ++r) {
        red[0][rg][q * 4 + r][cc] = accA[r];
        red[1][rg][q * 4 + r][cc] = accB[r];
      }
    }
    __syncthreads();
    if (kh == 0) {
#pragma unroll
      for (int r = 0; r < 4; ++r) {
        red[0][rg][q * 4 + r][cc] += accA[r];
        red[1][rg][q * 4 + r][cc] += accB[r];
      }
    }
    __syncthreads();

    // elementwise split: waves 0-3 layer0, waves 4-7 layer1 (write-through stores)
    const int rgE = row >> 4, r2 = row & 15;
    if (lowT) {
      if (s < 256) {
        float g[4];
#pragma unroll
        for (int gi = 0; gi < 4; ++gi) {
          bf16 pb = __builtin_bit_cast(bf16, (unsigned short)pgv[gi]);
          g[gi] = red[0][rgE][r2][gi * 4 + j2] + __bfloat162float(pb);
        }
        const float ii = sgm(g[0]), ff = sgm(g[1]), gg = tanhf(g[2]), oo = sgm(g[3]);
        cS = ff * cS + ii * gg;
        st_wt16(h0a + (size_t)(s + 1) * 65536 + ((size_t)bid * 64 + row) * 4 + j2,
                oo * tanhf(cS));
      }
    } else {
      if (s > 0) {
        float g[4];
#pragma unroll
        for (int gi = 0; gi < 4; ++gi)
          g[gi] = red[1][rgE][r2][gi * 4 + j2] + bfxr[gi];
        const float ii = sgm(g[0]), ff = sgm(g[1]), gg = tanhf(g[2]), oo = sgm(g[3]);
        cS = ff * cS + ii * gg;
        st_wt16(h1a + (size_t)s * 65536 + ((size_t)bid * 64 + row) * 4 + j2,
                oo * tanhf(cS));
      }
    }
    if (s < 256) barrier();
  }
}

extern "C" void kernel_launch(void* const* d_in, const int* in_sizes, int n_in,
                              void* d_out, int out_size, void* d_ws, size_t ws_size,
                              hipStream_t stream) {
  (void)in_sizes; (void)n_in; (void)out_size; (void)ws_size;
  const int*   tgt  = (const int*)d_in[0];
  const float* h0in = (const float*)d_in[1];
  const float* c0in = (const float*)d_in[2];
  const float* table= (const float*)d_in[3];
  const float* Wih0 = (const float*)d_in[4];
  const float* Whh0 = (const float*)d_in[5];
  const float* bih0 = (const float*)d_in[6];
  const float* bhh0 = (const float*)d_in[7];
  const float* Wp0  = (const float*)d_in[8];
  const float* bp0  = (const float*)d_in[9];
  const float* Wih1 = (const float*)d_in[10];
  const float* Whh1 = (const float*)d_in[11];
  const float* bih1 = (const float*)d_in[12];
  const float* bhh1 = (const float*)d_in[13];
  const float* Wp1  = (const float*)d_in[14];
  const float* bp1  = (const float*)d_in[15];
  float* out = (float*)d_out;

  char* w = (char*)d_ws;
  size_t off = 0;
  auto alloc = [&](size_t bytes) { char* p = w + off; off += (bytes + 255) & ~255ul; return p; };
  unsigned* arrive = (unsigned*)alloc(1024);
  float* bfx    = (float*)alloc(4096 * 4);
  bf16* embbf   = (bf16*)alloc(16384ul * 512 * 2);
  bf16* h0a     = (bf16*)alloc(257ul * 65536 * 2);
  bf16* h1a     = (bf16*)alloc(257ul * 65536 * 2);
  bf16* pre0    = (bf16*)alloc(16384ul * 4096 * 2);
  bf16* whh0b   = (bf16*)alloc(4096ul * 1024 * 2);
  bf16* whh1b   = (bf16*)alloc(4096ul * 1024 * 2);
  bf16* wih0b   = (bf16*)alloc(4096ul * 512 * 2);
  bf16* wp0b    = (bf16*)alloc(512ul * 1024 * 2);
  bf16* wp1b    = (bf16*)alloc(512ul * 1024 * 2);
  bf16* wfub    = (bf16*)alloc(4096ul * 1024 * 2);
  bf16* wp0thi  = (bf16*)alloc(1024ul * 512 * 2);
  bf16* wp0tlo  = (bf16*)alloc(1024ul * 512 * 2);

  embed_kernel<<<16384, 256, 0, stream>>>(tgt, table, out + OUT_EMB, embbf, arrive);
  prep_kernel<<<12800, 256, 0, stream>>>(Whh0, whh0b, Whh1, whh1b, Wih0, wih0b,
                                         Wp0, wp0b, Wp1, wp1b, h0in, h0a, h1a,
                                         wp0thi, wp0tlo);
  wfused_kernel<<<1024, 256, 0, stream>>>(Wih1, wp0thi, wp0tlo, wfub);
  bfx_kernel<<<16, 256, 0, stream>>>(Wih1, bp0, bih1, bhh1, bfx);
  pre0_gemm_kernel<<<16384, 256, 0, stream>>>(embbf, wih0b, bih0, bhh0, pre0);
  lstm_kernel<<<256, NTHR, 0, stream>>>(c0in, whh0b, wfub, whh1b, bfx, pre0,
                                        h0a, h1a, arrive);
  dim3 pg(2048, 2);
  proj_kernel<<<pg, 256, 0, stream>>>(h0a, h1a, wp0b, wp1b, bp0, bp1, out);
}

// Round 4
// 2700.769 us; speedup vs baseline: 6.2153x; 1.3284x over previous
//
#include <hip/hip_runtime.h>
#include <hip/hip_bf16.h>

typedef __hip_bfloat16 bf16;
typedef __attribute__((ext_vector_type(8))) short short8;
typedef __attribute__((ext_vector_type(4))) short sv4;
typedef __attribute__((ext_vector_type(4))) float f32x4;
typedef __attribute__((ext_vector_type(4))) unsigned uint4v;

#define NTHR 512
#define OUT_EMB 16777216ul   // T*L*B*IN floats
#define LEADER 256           // dedicated barrier-leader block

__device__ __forceinline__ float sgm(float x) { return 1.0f / (1.0f + expf(-x)); }
__device__ __forceinline__ short8 ld8(const bf16* p) {
  return *reinterpret_cast<const short8*>(p);
}

// device-coherent write-through store (no dirty L2 line -> no wbl2 needed at release)
__device__ __forceinline__ void st_wt16(bf16* p, float x) {
  unsigned v = (unsigned)__builtin_bit_cast(unsigned short, __float2bfloat16(x));
  asm volatile("global_store_short %0, %1, off sc0 sc1" :: "v"(p), "v"(v) : "memory");
}
__device__ __forceinline__ void st_wt32(unsigned* p, unsigned v) {
  asm volatile("global_store_dword %0, %1, off sc0 sc1" :: "v"(p), "v"(v) : "memory");
}
// fully-coherent poll load: sc0 bypasses L1, sc1 bypasses L2 (round-3 hang fix:
// sc1-only loads allocate in L1 and a non-streaming block re-reads stale L1 forever)
__device__ __forceinline__ unsigned ld_coh32(const unsigned* p) {
  unsigned v;
  asm volatile("global_load_dword %0, %1, off sc0 sc1\n\ts_waitcnt vmcnt(0)"
               : "=&v"(v) : "v"(p) : "memory");
  return v;
}
__device__ __forceinline__ uint4v ld_coh128(const unsigned* p) {
  uint4v v;
  asm volatile("global_load_dwordx4 %0, %1, off sc0 sc1\n\ts_waitcnt vmcnt(0)"
               : "=&v"(v) : "v"(p) : "memory");
  return v;
}

// kb-layout slab (64 rows x 1024 cols): element (row,col) at ((col>>2)*64+row)*4 + (col&3)
// -> each block's 4 owned columns are a contiguous 512B line-exclusive region per slab.
__device__ __forceinline__ short8 ld8kb(const bf16* slab, int row, int col) {
  const sv4* p = reinterpret_cast<const sv4*>(slab) + ((col >> 2) * 64 + row);
  sv4 a = p[0], b = p[64];
  return __builtin_shufflevector(a, b, 0, 1, 2, 3, 4, 5, 6, 7);
}

// ---- plain bf16 wave MMA: D[MT*16,16] += A[MT*16,kk] @ W[16,kk]^T ----
template<int MT>
__device__ __forceinline__ void wave_mma_bf(const bf16* __restrict__ A, int lda,
                                            const bf16* __restrict__ W, int ldw,
                                            int kk, f32x4* acc, int lane) {
  const int m = lane & 15, ko = (lane >> 4) * 8;
  const bf16* ap = A + (size_t)m * lda + ko;
  const bf16* wp = W + (size_t)m * ldw + ko;
#pragma unroll 4
  for (int k = 0; k < kk; k += 32) {
    short8 b = ld8(wp + k);
#pragma unroll
    for (int mt = 0; mt < MT; ++mt) {
      short8 a = ld8(ap + (size_t)mt * 16 * lda + k);
      acc[mt] = __builtin_amdgcn_mfma_f32_16x16x32_bf16(a, b, acc[mt], 0, 0, 0);
    }
  }
}

// ---- f32-A split MMA (prologue wfused only) ----
template<int MT>
__device__ __forceinline__ void wave_mma_f32a(const float* __restrict__ A, int lda,
                                              const bf16* __restrict__ W, int ldw,
                                              int kk, f32x4* acc, int lane) {
  const int m = lane & 15, ko = (lane >> 4) * 8;
  const float* ap = A + (size_t)m * lda + ko;
  const short* wp = reinterpret_cast<const short*>(W) + (size_t)m * ldw + ko;
#pragma unroll 2
  for (int k = 0; k < kk; k += 32) {
    short8 b = *reinterpret_cast<const short8*>(wp + k);
#pragma unroll
    for (int mt = 0; mt < MT; ++mt) {
      const float* s = ap + (size_t)mt * 16 * lda + k;
      float4 x0 = *reinterpret_cast<const float4*>(s);
      float4 x1 = *reinterpret_cast<const float4*>(s + 4);
      float xs[8] = {x0.x, x0.y, x0.z, x0.w, x1.x, x1.y, x1.z, x1.w};
      short8 ahi, alo;
#pragma unroll
      for (int j = 0; j < 8; ++j) {
        unsigned u  = __builtin_bit_cast(unsigned, xs[j]);
        float hf    = __builtin_bit_cast(float, u & 0xFFFF0000u);
        unsigned ul = __builtin_bit_cast(unsigned, xs[j] - hf);
        ahi[j] = (short)(u >> 16);
        alo[j] = (short)(ul >> 16);
      }
      acc[mt] = __builtin_amdgcn_mfma_f32_16x16x32_bf16(ahi, b, acc[mt], 0, 0, 0);
      acc[mt] = __builtin_amdgcn_mfma_f32_16x16x32_bf16(alo, b, acc[mt], 0, 0, 0);
    }
  }
}

// ---------------- prologue kernels ----------------

__global__ void embed_kernel(const int* __restrict__ tgt, const float* __restrict__ table,
                             float* __restrict__ embout, bf16* __restrict__ embbf,
                             unsigned* __restrict__ arrive) {
  const int row = blockIdx.x;                  // t*64+b
  const int tok = tgt[row];
  const float2* src = reinterpret_cast<const float2*>(table + (size_t)tok * 512);
  float2 v = src[threadIdx.x];
  reinterpret_cast<float2*>(embout + (size_t)row * 512)[threadIdx.x] = v;
  ushort2 h;
  h.x = __builtin_bit_cast(unsigned short, __float2bfloat16(v.x));
  h.y = __builtin_bit_cast(unsigned short, __float2bfloat16(v.y));
  reinterpret_cast<ushort2*>(embbf + (size_t)row * 512)[threadIdx.x] = h;
  // zero flags WRITE-THROUGH: a plain cached zero-store leaves a dirty line in one
  // XCD's L2 that can later be written back OVER live flags (stale-eviction hazard)
  if (row == 0 && threadIdx.x < 257) st_wt32(arrive + threadIdx.x, 0u);
}

__device__ __forceinline__ void cvt4(const float* __restrict__ src, bf16* __restrict__ dst,
                                     int i) {
  float4 v = *reinterpret_cast<const float4*>(src + i);
  sv4 o;
  o[0] = (short)__builtin_bit_cast(unsigned short, __float2bfloat16(v.x));
  o[1] = (short)__builtin_bit_cast(unsigned short, __float2bfloat16(v.y));
  o[2] = (short)__builtin_bit_cast(unsigned short, __float2bfloat16(v.z));
  o[3] = (short)__builtin_bit_cast(unsigned short, __float2bfloat16(v.w));
  *reinterpret_cast<sv4*>(dst + i) = o;
}

// fused weight-conversion + h-init + Wp0-transpose prologue (one launch)
__global__ void prep_kernel(const float* __restrict__ Whh0, bf16* __restrict__ whh0b,
                            const float* __restrict__ Whh1, bf16* __restrict__ whh1b,
                            const float* __restrict__ Wih0, bf16* __restrict__ wih0b,
                            const float* __restrict__ Wp0,  bf16* __restrict__ wp0b,
                            const float* __restrict__ Wp1,  bf16* __restrict__ wp1b,
                            const float* __restrict__ h0in, bf16* __restrict__ h0a,
                            bf16* __restrict__ h1a,
                            bf16* __restrict__ wp0thi, bf16* __restrict__ wp0tlo) {
  const int b = blockIdx.x, tid = threadIdx.x;
  if (b < 4096) {
    cvt4(Whh0, whh0b, b * 1024 + tid * 4);
  } else if (b < 8192) {
    cvt4(Whh1, whh1b, (b - 4096) * 1024 + tid * 4);
  } else if (b < 10240) {
    cvt4(Wih0, wih0b, (b - 8192) * 1024 + tid * 4);
  } else if (b < 10752) {
    cvt4(Wp0, wp0b, (b - 10240) * 1024 + tid * 4);
  } else if (b < 11264) {
    cvt4(Wp1, wp1b, (b - 10752) * 1024 + tid * 4);
  } else if (b < 11776) {
    const int idx = (b - 11264) * 256 + tid;          // 131072
    const int layer = idx >> 16, e = idx & 65535;
    const int row = e >> 10, col = e & 1023;
    bf16 v = __float2bfloat16(h0in[(size_t)layer * 65536 + e]);
    const size_t off = ((size_t)(col >> 2) * 64 + row) * 4 + (col & 3);
    if (layer) h1a[off] = v; else h0a[off] = v;
  } else {
    const int k = b - 11776;
    for (int j = tid; j < 512; j += blockDim.x) {
      const float x = Wp0[(size_t)j * 1024 + k];
      const bf16 h = __float2bfloat16(x);
      wp0thi[(size_t)k * 512 + j] = h;
      wp0tlo[(size_t)k * 512 + j] = __float2bfloat16(x - __bfloat162float(h));
    }
  }
}

// wfub[n][k] = bf16( sum_j Wih1[n][j] * Wp0[j][k] )
__global__ void wfused_kernel(const float* __restrict__ Wih1, const bf16* __restrict__ thi,
                              const bf16* __restrict__ tlo, bf16* __restrict__ wfub) {
  const int bx = blockIdx.x & 63, by = blockIdx.x >> 6;
  const int wv = threadIdx.x >> 6, lane = threadIdx.x & 63;
  const f32x4 vz = {0.f, 0.f, 0.f, 0.f};
  f32x4 acc[4] = {vz, vz, vz, vz};
  wave_mma_f32a<4>(Wih1 + (size_t)bx * 64 * 512, 512,
                   thi + (size_t)(by * 64 + wv * 16) * 512, 512, 512, acc, lane);
  wave_mma_f32a<4>(Wih1 + (size_t)bx * 64 * 512, 512,
                   tlo + (size_t)(by * 64 + wv * 16) * 512, 512, 512, acc, lane);
  const int cc = lane & 15, qq = lane >> 4;
#pragma unroll
  for (int mt = 0; mt < 4; ++mt)
#pragma unroll
    for (int rg = 0; rg < 4; ++rg)
      wfub[(size_t)(bx * 64 + mt * 16 + qq * 4 + rg) * 1024 + by * 64 + wv * 16 + cc] =
          __float2bfloat16(acc[mt][rg]);
}

// bfx[n] = bih1[n] + bhh1[n] + sum_j Wih1[n][j]*bp0[j]
__global__ void bfx_kernel(const float* __restrict__ Wih1, const float* __restrict__ bp0,
                           const float* __restrict__ bih1, const float* __restrict__ bhh1,
                           float* __restrict__ bfx) {
  const int n = blockIdx.x * blockDim.x + threadIdx.x;
  float s = bih1[n] + bhh1[n];
  for (int j = 0; j < 512; ++j)
    s += Wih1[(size_t)n * 512 + j] * bp0[j];
  bfx[n] = s;
}

// pre0 in block-exclusive layout: pre0[(((t*256+bid)*64+row)*4 + j2)*4 + gi]
__global__ void pre0_gemm_kernel(const bf16* __restrict__ embbf, const bf16* __restrict__ wih0b,
                                 const float* __restrict__ bih0, const float* __restrict__ bhh0,
                                 bf16* __restrict__ pre0) {
  const int ct = blockIdx.x & 63, rt = blockIdx.x >> 6;   // 64 col-tiles fastest
  const int wv = threadIdx.x >> 6, lane = threadIdx.x & 63;
  const f32x4 vz = {0.f, 0.f, 0.f, 0.f};
  f32x4 acc[4] = {vz, vz, vz, vz};
  wave_mma_bf<4>(embbf + (size_t)rt * 64 * 512, 512,
                 wih0b + (size_t)(ct * 64 + wv * 16) * 512, 512, 512, acc, lane);
  const int cc = lane & 15, qq = lane >> 4;
#pragma unroll
  for (int mt = 0; mt < 4; ++mt)
#pragma unroll
    for (int rg = 0; rg < 4; ++rg) {
      const int n = ct * 64 + wv * 16 + cc;
      const size_t R = (size_t)rt * 64 + mt * 16 + qq * 4 + rg;
      const int t = (int)(R >> 6), brow = (int)(R & 63);
      const int gi = n >> 10, c10 = n & 1023;
      pre0[((((size_t)t * 256 + (c10 >> 2)) * 64 + brow) * 4 + (c10 & 3)) * 4 + gi] =
          __float2bfloat16(acc[mt][rg] + bih0[n] + bhh0[n]);
    }
}

// out[t][l][brow][col] = h_l(t+1)[brow] @ Wp_l[col]^T + bp_l[col]   (h in kb-layout)
__global__ void proj_kernel(const bf16* __restrict__ h0a, const bf16* __restrict__ h1a,
                            const bf16* __restrict__ wp0b, const bf16* __restrict__ wp1b,
                            const float* __restrict__ bp0, const float* __restrict__ bp1,
                            float* __restrict__ out) {
  const int l = blockIdx.y;
  const bf16* hbase = (l ? h1a : h0a) + 65536;       // slab 1 onward
  const bf16* wp = l ? wp1b : wp0b;
  const float* bp = l ? bp1 : bp0;
  const int ct = blockIdx.x & 7, rt = blockIdx.x >> 3;
  const int wv = threadIdx.x >> 6, lane = threadIdx.x & 63;
  const f32x4 vz = {0.f, 0.f, 0.f, 0.f};
  f32x4 acc[4] = {vz, vz, vz, vz};
  const int m = lane & 15, ko = (lane >> 4) * 8;
  const bf16* wpp = wp + (size_t)(ct * 64 + wv * 16 + m) * 1024 + ko;
#pragma unroll 4
  for (int k = 0; k < 1024; k += 32) {
    short8 b = ld8(wpp + k);
#pragma unroll
    for (int mt = 0; mt < 4; ++mt) {
      const int R = rt * 64 + mt * 16 + m;
      const bf16* slab = hbase + (size_t)(R >> 6) * 65536;
      short8 a = ld8kb(slab, R & 63, ko + k);
      acc[mt] = __builtin_amdgcn_mfma_f32_16x16x32_bf16(a, b, acc[mt], 0, 0, 0);
    }
  }
  const int cc = lane & 15, qq = lane >> 4;
#pragma unroll
  for (int mt = 0; mt < 4; ++mt)
#pragma unroll
    for (int rg = 0; rg < 4; ++rg) {
      const int R = rt * 64 + mt * 16 + qq * 4 + rg;
      const int t = R >> 6, brow = R & 63;
      const int col = ct * 64 + wv * 16 + cc;
      out[((size_t)t * 2 + l) * 32768 + (size_t)brow * 512 + col] = acc[mt][rg] + bp[col];
    }
}

// ---------------- persistent recurrent kernel (fused layer pipeline) ----------------
// 256 worker blocks + 1 leader block, 512 thr; worker bid owns h-cols [bid*4, bid*4+4).
// Superstep s: layer0 step s AND layer1 step s-1; one global barrier per superstep.
// Barrier = gather/broadcast: workers store per-block flag (sc0 sc1); LEADER block's
// wave0 polls all 256 flags (64 lanes x dwordx4 coherent loads) and publishes a single
// epoch word; each worker's tid0 polls only that word. All poll loads are sc0 sc1
// (L1+L2 bypass) -- sc1-only loads allocate in L1 and a non-streaming leader would
// spin on a stale L1 line forever (round-3 hang).
__global__ void __launch_bounds__(NTHR, 2)
lstm_kernel(const float* __restrict__ c0in,
            const bf16* __restrict__ whh0b, const bf16* __restrict__ wfub,
            const bf16* __restrict__ whh1b, const float* __restrict__ bfx,
            const bf16* __restrict__ pre0,  // block-exclusive layout
            bf16* __restrict__ h0a,         // [257] slabs, kb-layout
            bf16* __restrict__ h1a,         // [257] slabs, kb-layout
            unsigned* __restrict__ arrive)  // [0..255] flags, [256] epoch
{
  const int bid = blockIdx.x, tid = threadIdx.x;

  if (bid == LEADER) {                       // barrier leader: gather flags, publish epoch
    if (tid < 64) {
      const unsigned* ap = arrive + tid * 4;
      unsigned* ep = arrive + 256;
      for (unsigned e = 1; e <= 256; ++e) {
        for (;;) {
          uint4v v = ld_coh128(ap);
          bool ok = v[0] >= e && v[1] >= e && v[2] >= e && v[3] >= e;
          if (__all(ok)) break;
        }
        if (tid == 0) st_wt32(ep, e);
      }
    }
    return;
  }

  __shared__ float red[2][4][16][20];        // pad 20: 2-way max on write/read
  __shared__ short wl[16384];                // Whh1 slice [32ks][4q][16cc][8e] = 32 KB
  const int wv = tid >> 6, lane = tid & 63;
  const int rg = wv & 3, kh = wv >> 2;       // row-group, K-half
  const int cc = lane & 15, q = lane >> 4;
  const int nrow = (cc >> 2) * 1024 + bid * 4 + (cc & 3);  // gate-col index
  const f32x4 vz = {0.f, 0.f, 0.f, 0.f};
  unsigned target = 0;

  // --- preload weights ---
  short8 wfA[16], wfB[16];
#pragma unroll
  for (int ks = 0; ks < 16; ++ks) {
    wfA[ks] = ld8(whh0b + (size_t)nrow * 1024 + kh * 512 + ks * 32 + q * 8);
    wfB[ks] = ld8(wfub  + (size_t)nrow * 1024 + kh * 512 + ks * 32 + q * 8);
  }
  // wl layout [ks][q][cc][8e]: quarter-wave ds_read_b128 spreads 2-way only
  for (int e8 = tid * 8; e8 < 16384; e8 += NTHR * 8) {
    const int ks = e8 >> 9, rem = e8 & 511;
    const int qq = rem >> 7, col = (rem >> 3) & 15;
    const int nr = (col >> 2) * 1024 + bid * 4 + (col & 3);
    *reinterpret_cast<short8*>(wl + e8) = ld8(whh1b + (size_t)nr * 1024 + ks * 32 + qq * 8);
  }

  // --- per-thread elementwise state: low waves (tid<256) own layer0, high own layer1 ---
  const bool lowT = tid < 256;
  const int et = tid & 255, row = et >> 2, j2 = et & 3;
  float cS, bfxr[4];
  if (lowT) {
    cS = c0in[(size_t)row * 1024 + bid * 4 + j2];
  } else {
    cS = c0in[65536 + (size_t)row * 1024 + bid * 4 + j2];
#pragma unroll
    for (int gi = 0; gi < 4; ++gi) bfxr[gi] = bfx[gi * 1024 + bid * 4 + j2];
  }

  __syncthreads();   // wl (LDS) ready

  auto barrier = [&]() {
    ++target;
    // drain this wave's sc1 write-through h stores (inline-asm stores are untracked)
    asm volatile("s_waitcnt vmcnt(0)" ::: "memory");
    __syncthreads();
    if (tid == 0) {
      st_wt32(arrive + bid, target);
      const unsigned* ep = arrive + 256;
      for (;;) {
        if (ld_coh32(ep) >= target) break;
        __builtin_amdgcn_s_sleep(1);
      }
    }
    __syncthreads();
  };

  const int arow = rg * 16 + cc, kbase = kh * 512 + q * 8;
  const short* wlw = wl + (kh * 16) * 512 + q * 128 + cc * 8;

  for (int s = 0; s <= 256; ++s) {
    // prefetch this superstep's layer-0 pre-activations (one 8B load; latency hides
    // under the MFMA block's h loads)
    sv4 pgv;
    if (lowT && s < 256)
      pgv = *reinterpret_cast<const sv4*>(
          pre0 + ((((size_t)s * 256 + bid) * 64 + row) * 4 + j2) * 4);

    f32x4 accA = vz, accB = vz;
    const bf16* s0 = h0a + (size_t)s * 65536;
    if (s < 256) {
#pragma unroll
      for (int ks = 0; ks < 16; ++ks) {
        short8 a = ld8kb(s0, arow, kbase + ks * 32);   // one h0 load feeds both layers
        accA = __builtin_amdgcn_mfma_f32_16x16x32_bf16(a, wfA[ks], accA, 0, 0, 0);
        accB = __builtin_amdgcn_mfma_f32_16x16x32_bf16(a, wfB[ks], accB, 0, 0, 0);
      }
    } else {
#pragma unroll
      for (int ks = 0; ks < 16; ++ks) {
        short8 a = ld8kb(s0, arow, kbase + ks * 32);
        accB = __builtin_amdgcn_mfma_f32_16x16x32_bf16(a, wfB[ks], accB, 0, 0, 0);
      }
    }
    if (s > 0) {
      const bf16* s1 = h1a + (size_t)(s - 1) * 65536;
#pragma unroll
      for (int ks = 0; ks < 16; ++ks)
        accB = __builtin_amdgcn_mfma_f32_16x16x32_bf16(
            ld8kb(s1, arow, kbase + ks * 32),
            *reinterpret_cast<const short8*>(wlw + ks * 512), accB, 0, 0, 0);
    }

    // fused dual reduction over K-halves
    if (kh == 1) {
#pragma unroll
      for (int r = 0; r < 4; ++r) {
        red[0][rg][q * 4 + r][cc] = accA[r];
        red[1][rg][q * 4 + r][cc] = accB[r];
      }
    }
    __syncthreads();
    if (kh == 0) {
#pragma unroll
      for (int r = 0; r < 4; ++r) {
        red[0][rg][q * 4 + r][cc] += accA[r];
        red[1][rg][q * 4 + r][cc] += accB[r];
      }
    }
    __syncthreads();

    // elementwise split: waves 0-3 layer0, waves 4-7 layer1 (write-through stores)
    const int rgE = row >> 4, r2 = row & 15;
    if (lowT) {
      if (s < 256) {
        float g[4];
#pragma unroll
        for (int gi = 0; gi < 4; ++gi) {
          bf16 pb = __builtin_bit_cast(bf16, (unsigned short)pgv[gi]);
          g[gi] = red[0][rgE][r2][gi * 4 + j2] + __bfloat162float(pb);
        }
        const float ii = sgm(g[0]), ff = sgm(g[1]), gg = tanhf(g[2]), oo = sgm(g[3]);
        cS = ff * cS + ii * gg;
        st_wt16(h0a + (size_t)(s + 1) * 65536 + ((size_t)bid * 64 + row) * 4 + j2,
                oo * tanhf(cS));
      }
    } else {
      if (s > 0) {
        float g[4];
#pragma unroll
        for (int gi = 0; gi < 4; ++gi)
          g[gi] = red[1][rgE][r2][gi * 4 + j2] + bfxr[gi];
        const float ii = sgm(g[0]), ff = sgm(g[1]), gg = tanhf(g[2]), oo = sgm(g[3]);
        cS = ff * cS + ii * gg;
        st_wt16(h1a + (size_t)s * 65536 + ((size_t)bid * 64 + row) * 4 + j2,
                oo * tanhf(cS));
      }
    }
    if (s < 256) barrier();
  }
}

extern "C" void kernel_launch(void* const* d_in, const int* in_sizes, int n_in,
                              void* d_out, int out_size, void* d_ws, size_t ws_size,
                              hipStream_t stream) {
  (void)in_sizes; (void)n_in; (void)out_size; (void)ws_size;
  const int*   tgt  = (const int*)d_in[0];
  const float* h0in = (const float*)d_in[1];
  const float* c0in = (const float*)d_in[2];
  const float* table= (const float*)d_in[3];
  const float* Wih0 = (const float*)d_in[4];
  const float* Whh0 = (const float*)d_in[5];
  const float* bih0 = (const float*)d_in[6];
  const float* bhh0 = (const float*)d_in[7];
  const float* Wp0  = (const float*)d_in[8];
  const float* bp0  = (const float*)d_in[9];
  const float* Wih1 = (const float*)d_in[10];
  const float* Whh1 = (const float*)d_in[11];
  const float* bih1 = (const float*)d_in[12];
  const float* bhh1 = (const float*)d_in[13];
  const float* Wp1  = (const float*)d_in[14];
  const float* bp1  = (const float*)d_in[15];
  float* out = (float*)d_out;

  char* w = (char*)d_ws;
  size_t off = 0;
  auto alloc = [&](size_t bytes) { char* p = w + off; off += (bytes + 255) & ~255ul; return p; };
  unsigned* arrive = (unsigned*)alloc(2048);   // 256 flags + epoch word @ index 256
  float* bfx    = (float*)alloc(4096 * 4);
  bf16* embbf   = (bf16*)alloc(16384ul * 512 * 2);
  bf16* h0a     = (bf16*)alloc(257ul * 65536 * 2);
  bf16* h1a     = (bf16*)alloc(257ul * 65536 * 2);
  bf16* pre0    = (bf16*)alloc(16384ul * 4096 * 2);
  bf16* whh0b   = (bf16*)alloc(4096ul * 1024 * 2);
  bf16* whh1b   = (bf16*)alloc(4096ul * 1024 * 2);
  bf16* wih0b   = (bf16*)alloc(4096ul * 512 * 2);
  bf16* wp0b    = (bf16*)alloc(512ul * 1024 * 2);
  bf16* wp1b    = (bf16*)alloc(512ul * 1024 * 2);
  bf16* wfub    = (bf16*)alloc(4096ul * 1024 * 2);
  bf16* wp0thi  = (bf16*)alloc(1024ul * 512 * 2);
  bf16* wp0tlo  = (bf16*)alloc(1024ul * 512 * 2);

  embed_kernel<<<16384, 256, 0, stream>>>(tgt, table, out + OUT_EMB, embbf, arrive);
  prep_kernel<<<12800, 256, 0, stream>>>(Whh0, whh0b, Whh1, whh1b, Wih0, wih0b,
                                         Wp0, wp0b, Wp1, wp1b, h0in, h0a, h1a,
                                         wp0thi, wp0tlo);
  wfused_kernel<<<1024, 256, 0, stream>>>(Wih1, wp0thi, wp0tlo, wfub);
  bfx_kernel<<<16, 256, 0, stream>>>(Wih1, bp0, bih1, bhh1, bfx);
  pre0_gemm_kernel<<<16384, 256, 0, stream>>>(embbf, wih0b, bih0, bhh0, pre0);
  lstm_kernel<<<257, NTHR, 0, stream>>>(c0in, whh0b, wfub, whh1b, bfx, pre0,
                                        h0a, h1a, arrive);
  dim3 pg(2048, 2);
  proj_kernel<<<pg, 256, 0, stream>>>(h0a, h1a, wp0b, wp1b, bp0, bp1, out);
}